// Round 1
// baseline (373.530 us; speedup 1.0000x reference)
//
#include <hip/hip_runtime.h>

#define STATE 2048
#define BLOCK 256
#define GRID  2048

// d_ws[0] holds a double accumulator.
__global__ void trisum_zero_ws(double* __restrict__ ws) {
    if (blockIdx.x == 0 && threadIdx.x == 0) ws[0] = 0.0;
}

__global__ __launch_bounds__(BLOCK) void trisum_main(
        const float* __restrict__ input,
        const float* __restrict__ weights,
        const int4*  __restrict__ idxs4,   // idxs viewed as int4; 3 int4 = 4 triples
        int ngroups,                       // ntriples / 4
        double* __restrict__ ws) {
    __shared__ float s_in[STATE];
    __shared__ float s_w[STATE];
    // Only weights[0:2048] are ever indexed (idxs col 0 in [0, STATE)).
    for (int i = threadIdx.x; i < STATE; i += BLOCK) {
        s_in[i] = input[i];
        s_w[i]  = weights[i];
    }
    __syncthreads();

    float acc = 0.0f;
    const int stride = gridDim.x * blockDim.x;
    for (int g = blockIdx.x * blockDim.x + threadIdx.x; g < ngroups; g += stride) {
        // 4 triples = 12 ints = 48 bytes = 3 aligned int4 loads
        const int4 v0 = idxs4[3 * g + 0];
        const int4 v1 = idxs4[3 * g + 1];
        const int4 v2 = idxs4[3 * g + 2];
        acc += s_w[v0.x] * s_in[v0.y] * s_in[v0.z];
        acc += s_w[v0.w] * s_in[v1.x] * s_in[v1.y];
        acc += s_w[v1.z] * s_in[v1.w] * s_in[v2.x];
        acc += s_w[v2.y] * s_in[v2.z] * s_in[v2.w];
    }

    // wave64 butterfly reduce
    #pragma unroll
    for (int off = 32; off > 0; off >>= 1)
        acc += __shfl_down(acc, off, 64);

    __shared__ double s_part[BLOCK / 64];
    const int wid  = threadIdx.x >> 6;
    const int lane = threadIdx.x & 63;
    if (lane == 0) s_part[wid] = (double)acc;
    __syncthreads();
    if (threadIdx.x == 0) {
        double b = 0.0;
        #pragma unroll
        for (int w = 0; w < BLOCK / 64; ++w) b += s_part[w];
        atomicAdd(ws, b);   // device-scope by default; ~2048 atomics total
    }
}

__global__ void trisum_finalize(const double* __restrict__ ws, float* __restrict__ out) {
    if (blockIdx.x == 0 && threadIdx.x == 0) out[0] = (float)ws[0];
}

extern "C" void kernel_launch(void* const* d_in, const int* in_sizes, int n_in,
                              void* d_out, int out_size, void* d_ws, size_t ws_size,
                              hipStream_t stream) {
    const float* input   = (const float*)d_in[0];
    const float* weights = (const float*)d_in[1];
    const int*   idxs    = (const int*)d_in[2];
    // d_in[3] (idxs_bw) is not needed for the forward pass.

    const int ntriples = in_sizes[2] / 3;      // 16,777,216
    const int ngroups  = ntriples / 4;         // 4,194,304 (ntriples % 4 == 0)

    float*  out = (float*)d_out;
    double* ws  = (double*)d_ws;

    trisum_zero_ws<<<1, 64, 0, stream>>>(ws);
    trisum_main<<<GRID, BLOCK, 0, stream>>>(input, weights,
                                            (const int4*)idxs, ngroups, ws);
    trisum_finalize<<<1, 64, 0, stream>>>(ws, out);
}

// Round 2
// 372.794 us; speedup vs baseline: 1.0020x; 1.0020x over previous
//
#include <hip/hip_runtime.h>

#define STATE 2048
#define BLOCK 256
#define GRID  2048

__global__ __launch_bounds__(BLOCK) void trisum_main(
        const float* __restrict__ input,
        const float* __restrict__ weights,
        const int4*  __restrict__ idxs4,   // idxs as int4; 6 int4 = 8 triples
        int ngroups8,                      // ntriples / 8
        double* __restrict__ partials) {
    __shared__ float s_in[STATE];
    __shared__ float s_w[STATE];
    // Only weights[0:2048] are ever indexed (idxs col 0 in [0, STATE)).
    for (int i = threadIdx.x; i < STATE; i += BLOCK) {
        s_in[i] = input[i];
        s_w[i]  = weights[i];
    }
    __syncthreads();

    float acc = 0.0f;
    const int stride = GRID * BLOCK;
    #pragma unroll 2
    for (int g = blockIdx.x * BLOCK + threadIdx.x; g < ngroups8; g += stride) {
        // 8 triples = 24 ints = 96 contiguous bytes per thread = 6 int4 loads
        const int4 v0 = idxs4[6 * g + 0];
        const int4 v1 = idxs4[6 * g + 1];
        const int4 v2 = idxs4[6 * g + 2];
        const int4 v3 = idxs4[6 * g + 3];
        const int4 v4 = idxs4[6 * g + 4];
        const int4 v5 = idxs4[6 * g + 5];
        acc += s_w[v0.x] * s_in[v0.y] * s_in[v0.z];
        acc += s_w[v0.w] * s_in[v1.x] * s_in[v1.y];
        acc += s_w[v1.z] * s_in[v1.w] * s_in[v2.x];
        acc += s_w[v2.y] * s_in[v2.z] * s_in[v2.w];
        acc += s_w[v3.x] * s_in[v3.y] * s_in[v3.z];
        acc += s_w[v3.w] * s_in[v4.x] * s_in[v4.y];
        acc += s_w[v4.z] * s_in[v4.w] * s_in[v5.x];
        acc += s_w[v5.y] * s_in[v5.z] * s_in[v5.w];
    }

    // wave64 butterfly reduce (f32), then per-block double partial
    #pragma unroll
    for (int off = 32; off > 0; off >>= 1)
        acc += __shfl_down(acc, off, 64);

    __shared__ double s_part[BLOCK / 64];
    if ((threadIdx.x & 63) == 0) s_part[threadIdx.x >> 6] = (double)acc;
    __syncthreads();
    if (threadIdx.x == 0) {
        partials[blockIdx.x] = s_part[0] + s_part[1] + s_part[2] + s_part[3];
    }
}

__global__ __launch_bounds__(256) void trisum_finalize(
        const double* __restrict__ partials, float* __restrict__ out) {
    double a = 0.0;
    for (int i = threadIdx.x; i < GRID; i += 256) a += partials[i];
    #pragma unroll
    for (int off = 32; off > 0; off >>= 1)
        a += __shfl_down(a, off, 64);
    __shared__ double s_part[4];
    if ((threadIdx.x & 63) == 0) s_part[threadIdx.x >> 6] = a;
    __syncthreads();
    if (threadIdx.x == 0)
        out[0] = (float)(s_part[0] + s_part[1] + s_part[2] + s_part[3]);
}

extern "C" void kernel_launch(void* const* d_in, const int* in_sizes, int n_in,
                              void* d_out, int out_size, void* d_ws, size_t ws_size,
                              hipStream_t stream) {
    const float* input   = (const float*)d_in[0];
    const float* weights = (const float*)d_in[1];
    const int*   idxs    = (const int*)d_in[2];
    // d_in[3] (idxs_bw) is not needed for the forward pass.

    const int ntriples = in_sizes[2] / 3;      // 16,777,216
    const int ngroups8 = ntriples / 8;         // 2,097,152 (ntriples % 8 == 0)

    float*  out      = (float*)d_out;
    double* partials = (double*)d_ws;          // GRID doubles; every slot written

    trisum_main<<<GRID, BLOCK, 0, stream>>>(input, weights,
                                            (const int4*)idxs, ngroups8, partials);
    trisum_finalize<<<1, 256, 0, stream>>>(partials, out);
}